// Round 17
// baseline (165.992 us; speedup 1.0000x reference)
//
#include <hip/hip_runtime.h>
#include <hip/hip_bf16.h>
#include <stdint.h>

typedef __bf16 bf16_t;
typedef __bf16 bf16x8 __attribute__((ext_vector_type(8)));
typedef __bf16 bf16x4 __attribute__((ext_vector_type(4)));
typedef float f32x4 __attribute__((ext_vector_type(4)));

#define DEVI static __device__ __forceinline__
#define SCHED0 __builtin_amdgcn_sched_barrier(0)
#define VMCNT0 asm volatile("s_waitcnt vmcnt(0)" ::: "memory")

// async global->LDS, 16B per lane. LDS dest = wave-uniform base + lane*16 (HW).
DEVI void gload_lds16(const void* g, void* lds) {
  __builtin_amdgcn_global_load_lds(
      (const __attribute__((address_space(1))) unsigned int*)g,
      (__attribute__((address_space(3))) unsigned int*)lds, 16, 0, 0);
}

// ---------------- merged prep: cvt x/w_in/w_c + transposed cvt of w_out +
// fused bias b2 = bc + bo @ Wc^T, one launch, block-range partitioned -------
__global__ void prep(const float* __restrict__ x, bf16_t* __restrict__ xb, int na4,
                     const float* __restrict__ w_in, bf16_t* __restrict__ wqb, int nb4,
                     const float* __restrict__ w_c, bf16_t* __restrict__ wcb, int nc4,
                     const float* __restrict__ w_out, bf16_t* __restrict__ wotb,
                     const float* __restrict__ bo, const float* __restrict__ bc,
                     float* __restrict__ b2) {
  __shared__ float ls[32][36];
  const int bid = blockIdx.x, tid = threadIdx.x;
  const int ncvt = (na4 + nb4 + nc4) >> 8;  // exact multiple of 256
  if (bid < ncvt) {
    int j = bid * 256 + tid;
    const float* src;
    bf16_t* dst;
    if (j < na4) {
      src = x; dst = xb;
    } else {
      j -= na4;
      if (j < nb4) {
        src = w_in; dst = wqb;
      } else {
        j -= nb4;
        src = w_c; dst = wcb;
      }
    }
    float4 v = ((const float4*)src)[j];
    bf16x4 o;
    o[0] = (bf16_t)v.x; o[1] = (bf16_t)v.y; o[2] = (bf16_t)v.z; o[3] = (bf16_t)v.w;
    ((bf16x4*)dst)[j] = o;
  } else if (bid < ncvt + 1024) {
    // 32x32 transpose-cvt tile of w_out (1024x1024)
    const int idx = bid - ncvt;
    const int C0 = (idx & 31) * 32, R0 = (idx >> 5) * 32;
    {
      const int r = tid >> 3, c4 = (tid & 7) * 4;
      float4 v = *(const float4*)&w_out[(size_t)(R0 + r) * 1024 + C0 + c4];
      ls[r][c4 + 0] = v.x; ls[r][c4 + 1] = v.y; ls[r][c4 + 2] = v.z; ls[r][c4 + 3] = v.w;
    }
    __syncthreads();
    {
      const int c = tid >> 3, r4 = (tid & 7) * 4;
      bf16x4 o;
#pragma unroll
      for (int j = 0; j < 4; j++) o[j] = (bf16_t)ls[r4 + j][c];
      *(bf16x4*)&wotb[(size_t)(C0 + c) * 1024 + R0 + r4] = o;
    }
  } else {
    // bias2k: 256 blocks x 4 waves -> 1024 outputs
    const int wid = ((bid - ncvt - 1024) << 2) + (tid >> 6);
    const int ln = tid & 63;
    float s = 0.f;
    for (int k = ln; k < 1024; k += 64) s += bo[k] * w_c[(size_t)wid * 1024 + k];
#pragma unroll
    for (int o = 32; o; o >>= 1) s += __shfl_xor(s, o, 64);
    if (ln == 0) b2[wid] = s + bc[wid];
  }
}

// ============ 128x256 QKV GEMM, 2-phase, 8 waves (round-15 proven form) ====
// C[8192,3072] = A @ B^T + bias -> scattered Q/K/V^T. Wave tile 64x64.
// LDS 96KB, 1 block/CU, single barrier per K-step (counted-vmcnt regressed).
__global__ __launch_bounds__(512, 2) void gemm_qkv(
    const bf16_t* __restrict__ A, const bf16_t* __restrict__ B,
    const float* __restrict__ bias,
    bf16_t* __restrict__ qo, bf16_t* __restrict__ ko, bf16_t* __restrict__ vo) {
  __shared__ alignas(16) char lds[98304];  // A: [0,32K) dbuf, B: [32K,96K) dbuf
  const int K = 1024;
  const int tid = threadIdx.x;
  const int wave = tid >> 6, lane = tid & 63;
  const int lr = lane & 15, lg = (lane >> 4) & 3;
  const int wm = wave >> 2, wn = wave & 3;

  // L2-chunked XCD mapping: xcd owns 8 bm-tiles (A-chunk 2MB, L2-fits);
  // consecutive idx walks bm within chunk (B-panel 512KB shared).
  const int lin = blockIdx.x;
  const int xcd = lin & 7, idx = lin >> 3;        // idx 0..95
  const int bm = (xcd * 8 + (idx & 7)) * 128;
  const int bn = (idx >> 3) * 256;

  const int srow = tid >> 3;                      // 0..63
  const int schunk = (tid & 7) ^ (srow & 7);      // pre-swizzled global chunk

  auto stage = [&](int buf, int t) {
#pragma unroll
    for (int u = 0; u < 2; u++) {
      const bf16_t* ga = A + (size_t)(bm + u * 64 + srow) * K + t * 64 + schunk * 8;
      gload_lds16(ga, lds + buf * 16384 + u * 8192 + wave * 1024);
    }
#pragma unroll
    for (int u = 0; u < 4; u++) {
      const bf16_t* gb = B + (size_t)(bn + u * 64 + srow) * K + t * 64 + schunk * 8;
      gload_lds16(gb, lds + 32768 + buf * 32768 + u * 8192 + wave * 1024);
    }
  };
  auto ldA = [&](int buf, int mf, int kk) -> bf16x8 {
    const int row = wm * 64 + mf * 16 + lr;
    return *(const bf16x8*)(lds + buf * 16384 + row * 128 +
                            ((((kk << 2) + lg) ^ (row & 7)) << 4));
  };
  auto ldB = [&](int buf, int nf, int kk) -> bf16x8 {
    const int row = wn * 64 + nf * 16 + lr;
    return *(const bf16x8*)(lds + 32768 + buf * 32768 + row * 128 +
                            ((((kk << 2) + lg) ^ (row & 7)) << 4));
  };

  f32x4 acc[4][4];
#pragma unroll
  for (int m = 0; m < 4; m++)
#pragma unroll
    for (int n = 0; n < 4; n++) acc[m][n] = (f32x4){0.f, 0.f, 0.f, 0.f};

  stage(0, 0);
  VMCNT0;
  __builtin_amdgcn_s_barrier();
  SCHED0;

  auto kstep = [&](int buf, int t, bool pre) {
    if (pre) stage(buf ^ 1, t + 1);  // prefetch: whole compute phase to land
    SCHED0;
#pragma unroll
    for (int kk = 0; kk < 2; kk++) {
      bf16x8 af[4], bfr[4];
#pragma unroll
      for (int m = 0; m < 4; m++) af[m] = ldA(buf, m, kk);
#pragma unroll
      for (int n = 0; n < 4; n++) bfr[n] = ldB(buf, n, kk);
#pragma unroll
      for (int m = 0; m < 4; m++)
#pragma unroll
        for (int n = 0; n < 4; n++)
          acc[m][n] = __builtin_amdgcn_mfma_f32_16x16x32_bf16(af[m], bfr[n], acc[m][n], 0, 0, 0);
    }
    SCHED0;
    VMCNT0;
    __builtin_amdgcn_s_barrier();
    SCHED0;
  };
  for (int t = 0; t < 16; t += 2) {
    kstep(0, t, true);
    kstep(1, t + 1, t + 2 < 16);
  }

  // ---- epilogue: LDS roundtrip, coalesced scatter to Q/K/V^T -------------
  const int which = bn >> 10;  // 0=Q 1=K 2=V (256-tile wholly in one section)
  if (which != 2) {
    bf16_t(*ep)[264] = (bf16_t(*)[264])lds;  // [128][264] = 67.6 KB
#pragma unroll
    for (int nf = 0; nf < 4; nf++) {
      const int col = wn * 64 + nf * 16 + lr;
      const float bv = bias[bn + col];
#pragma unroll
      for (int mf = 0; mf < 4; mf++)
#pragma unroll
        for (int i = 0; i < 4; i++) {
          const int row = wm * 64 + mf * 16 + lg * 4 + i;
          float v = acc[mf][nf][i] + bv;
          if (which == 0) v *= 0.18033688f;  // fold (1/sqrt(64))*log2(e)
          ep[row][col] = (bf16_t)v;
        }
    }
    __syncthreads();
#pragma unroll
    for (int itr = 0; itr < 8; itr++) {
      const int unit = itr * 512 + tid;  // 128 rows x 32 chunks
      const int row = unit >> 5, c0 = (unit & 31) * 8;
      bf16x8 val = *(const bf16x8*)&ep[row][c0];
      const int gr = bm + row, b = gr >> 10, t = gr & 1023;
      const int e = bn + c0, h = (e & 1023) >> 6, d = e & 63;
      bf16_t* dst = (which == 0 ? qo : ko) + ((size_t)(b * 16 + h) * 1024 + t) * 64 + d;
      *(bf16x8*)dst = val;
    }
  } else {
    bf16_t(*ep)[136] = (bf16_t(*)[136])lds;  // transposed [256][136] = 69.6 KB
#pragma unroll
    for (int nf = 0; nf < 4; nf++) {
      const int col = wn * 64 + nf * 16 + lr;
      const float bv = bias[bn + col];
#pragma unroll
      for (int mf = 0; mf < 4; mf++)
#pragma unroll
        for (int i = 0; i < 4; i++) {
          const int row = wm * 64 + mf * 16 + lg * 4 + i;
          ep[col][row] = (bf16_t)(acc[mf][nf][i] + bv);
        }
    }
    __syncthreads();
#pragma unroll
    for (int itr = 0; itr < 8; itr++) {
      const int unit = itr * 512 + tid;  // 256 d-rows x 16 chunks of t
      const int r = unit >> 4, c0 = (unit & 15) * 8;
      bf16x8 val = *(const bf16x8*)&ep[r][c0];
      const int e = (bn - 2048) + r, h = e >> 6, d = e & 63;
      const int gt = bm + c0, b = gt >> 10, t = gt & 1023;
      bf16_t* dst = vo + ((size_t)(b * 16 + h) * 64 + d) * 1024 + t;
      *(bf16x8*)dst = val;
    }
  }
}

// ============ 128x256 FINAL GEMM, f32 out (round-15 proven form) ===========
__global__ __launch_bounds__(512, 2) void gemm_fin(
    const bf16_t* __restrict__ A, const bf16_t* __restrict__ B,
    const float* __restrict__ bias, float* __restrict__ Cout) {
  __shared__ alignas(16) char lds[98304];
  const int K = 1024, N = 1024;
  const int tid = threadIdx.x;
  const int wave = tid >> 6, lane = tid & 63;
  const int lr = lane & 15, lg = (lane >> 4) & 3;
  const int wm = wave >> 2, wn = wave & 3;

  const int lin = blockIdx.x;                 // 0..255
  const int xcd = lin & 7, idx = lin >> 3;    // idx 0..31
  const int bm = (xcd * 8 + (idx & 7)) * 128;
  const int bn = (idx >> 3) * 256;

  const int srow = tid >> 3;
  const int schunk = (tid & 7) ^ (srow & 7);

  auto stage = [&](int buf, int t) {
#pragma unroll
    for (int u = 0; u < 2; u++) {
      const bf16_t* ga = A + (size_t)(bm + u * 64 + srow) * K + t * 64 + schunk * 8;
      gload_lds16(ga, lds + buf * 16384 + u * 8192 + wave * 1024);
    }
#pragma unroll
    for (int u = 0; u < 4; u++) {
      const bf16_t* gb = B + (size_t)(bn + u * 64 + srow) * K + t * 64 + schunk * 8;
      gload_lds16(gb, lds + 32768 + buf * 32768 + u * 8192 + wave * 1024);
    }
  };
  auto ldA = [&](int buf, int mf, int kk) -> bf16x8 {
    const int row = wm * 64 + mf * 16 + lr;
    return *(const bf16x8*)(lds + buf * 16384 + row * 128 +
                            ((((kk << 2) + lg) ^ (row & 7)) << 4));
  };
  auto ldB = [&](int buf, int nf, int kk) -> bf16x8 {
    const int row = wn * 64 + nf * 16 + lr;
    return *(const bf16x8*)(lds + 32768 + buf * 32768 + row * 128 +
                            ((((kk << 2) + lg) ^ (row & 7)) << 4));
  };

  f32x4 acc[4][4];
#pragma unroll
  for (int m = 0; m < 4; m++)
#pragma unroll
    for (int n = 0; n < 4; n++) acc[m][n] = (f32x4){0.f, 0.f, 0.f, 0.f};

  stage(0, 0);
  VMCNT0;
  __builtin_amdgcn_s_barrier();
  SCHED0;

  auto kstep = [&](int buf, int t, bool pre) {
    if (pre) stage(buf ^ 1, t + 1);
    SCHED0;
#pragma unroll
    for (int kk = 0; kk < 2; kk++) {
      bf16x8 af[4], bfr[4];
#pragma unroll
      for (int m = 0; m < 4; m++) af[m] = ldA(buf, m, kk);
#pragma unroll
      for (int n = 0; n < 4; n++) bfr[n] = ldB(buf, n, kk);
#pragma unroll
      for (int m = 0; m < 4; m++)
#pragma unroll
        for (int n = 0; n < 4; n++)
          acc[m][n] = __builtin_amdgcn_mfma_f32_16x16x32_bf16(af[m], bfr[n], acc[m][n], 0, 0, 0);
    }
    SCHED0;
    VMCNT0;
    __builtin_amdgcn_s_barrier();
    SCHED0;
  };
  for (int t = 0; t < 16; t += 2) {
    kstep(0, t, true);
    kstep(1, t + 1, t + 2 < 16);
  }

  // 2-pass coalesced f32 epilogue: [64][264] f32 = 67.6 KB
  float(*epf)[264] = (float(*)[264])lds;
#pragma unroll
  for (int p = 0; p < 2; ++p) {
    if (wm == p) {
#pragma unroll
      for (int nf = 0; nf < 4; nf++) {
        const int col = wn * 64 + nf * 16 + lr;
        const float bv = bias[bn + col];
#pragma unroll
        for (int mf = 0; mf < 4; mf++)
#pragma unroll
          for (int i = 0; i < 4; i++)
            epf[mf * 16 + lg * 4 + i][col] = acc[mf][nf][i] + bv;
      }
    }
    __syncthreads();
#pragma unroll
    for (int itr = 0; itr < 8; ++itr) {
      const int unit = itr * 512 + tid;  // 64 rows x 64 float4
      const int row = unit >> 6, c4 = (unit & 63) * 4;
      float4 v = *(const float4*)&epf[row][c4];
      *(float4*)&Cout[(size_t)(bm + p * 64 + row) * N + bn + c4] = v;
    }
    __syncthreads();
  }
}

// ---------------- 128x128 double-buffered GEMM (wcomb only) ----------------
__global__ __launch_bounds__(256, 2) void gemm_db(
    const bf16_t* __restrict__ A, const bf16_t* __restrict__ B,
    bf16_t* __restrict__ Cout, int M, int N, int K) {
  __shared__ alignas(16) char lds[65536];
  const int tid = threadIdx.x;
  const int wave = tid >> 6, lane = tid & 63;
  const int lr = lane & 15, lg = lane >> 4;
  const int wr = wave >> 1, wc = wave & 1;

  const int gx = gridDim.x;
  const int lin = blockIdx.y * gx + blockIdx.x;
  const int xcd = lin & 7, idx = lin >> 3;
  const int bmx = gx >> 3;
  const int bm = (xcd * bmx + (bmx > 1 ? idx % bmx : 0)) * 128;
  const int bn = (bmx > 1 ? idx / bmx : idx) * 128;

  const int srow = tid >> 3;
  const int schunk = (tid & 7) ^ (srow & 7);

  auto stage = [&](int buf, int t) {
#pragma unroll
    for (int i = 0; i < 4; i++) {
      const bf16_t* ga = A + (size_t)(bm + srow + i * 32) * K + t * 64 + schunk * 8;
      gload_lds16(ga, lds + buf * 16384 + i * 4096 + wave * 1024);
      const bf16_t* gb = B + (size_t)(bn + srow + i * 32) * K + t * 64 + schunk * 8;
      gload_lds16(gb, lds + 32768 + buf * 16384 + i * 4096 + wave * 1024);
    }
  };
  auto ldA = [&](int buf, int mf, int kk) -> bf16x8 {
    const int row = wr * 64 + mf * 16 + lr;
    return *(const bf16x8*)(lds + buf * 16384 + row * 128 +
                            ((((kk << 2) + lg) ^ (row & 7)) << 4));
  };
  auto ldB = [&](int buf, int nf, int kk) -> bf16x8 {
    const int row = wc * 64 + nf * 16 + lr;
    return *(const bf16x8*)(lds + 32768 + buf * 16384 + row * 128 +
                            ((((kk << 2) + lg) ^ (row & 7)) << 4));
  };

  f32x4 acc[4][4];
#pragma unroll
  for (int m = 0; m < 4; m++)
#pragma unroll
    for (int n = 0; n < 4; n++) acc[m][n] = (f32x4){0.f, 0.f, 0.f, 0.f};

  const int nK = K >> 6;

  stage(0, 0);
  VMCNT0;
  __builtin_amdgcn_s_barrier();
  SCHED0;

  auto kstep = [&](int buf, int t, bool pre) {
    if (pre) stage(buf ^ 1, t + 1);
    SCHED0;
#pragma unroll
    for (int kk = 0; kk < 2; kk++) {
      bf16x8 af[4], bfr[4];
#pragma unroll
      for (int m = 0; m < 4; m++) af[m] = ldA(buf, m, kk);
#pragma unroll
      for (int n = 0; n < 4; n++) bfr[n] = ldB(buf, n, kk);
#pragma unroll
      for (int m = 0; m < 4; m++)
#pragma unroll
        for (int n = 0; n < 4; n++)
          acc[m][n] = __builtin_amdgcn_mfma_f32_16x16x32_bf16(af[m], bfr[n], acc[m][n], 0, 0, 0);
    }
    SCHED0;
    VMCNT0;
    __builtin_amdgcn_s_barrier();
    SCHED0;
  };
  for (int t = 0; t < nK; t += 2) {
    kstep(0, t, true);
    kstep(1, t + 1, t + 2 < nK);
  }

  bf16_t(*ep)[132] = (bf16_t(*)[132])lds;
#pragma unroll
  for (int nf = 0; nf < 4; nf++) {
    const int col = wc * 64 + nf * 16 + lr;
#pragma unroll
    for (int mf = 0; mf < 4; mf++)
#pragma unroll
      for (int i = 0; i < 4; i++)
        ep[wr * 64 + mf * 16 + lg * 4 + i][col] = (bf16_t)acc[mf][nf][i];
  }
  __syncthreads();
#pragma unroll
  for (int rr = 0; rr < 8; rr++) {
    const int row = rr * 16 + (tid >> 4);
    const int c0 = (tid & 15) * 8;
    bf16x8 val = *(const bf16x8*)&ep[row][c0];
    *(bf16x8*)&((bf16_t*)Cout)[(size_t)(bm + row) * N + bn + c0] = val;
  }
}

// ---------------- causal flash attention v5: QBLK=256, 8 waves -------------
// grid (2, 128). Block handles q-super-tile pair {bx, 3-bx} (256 rows each):
// constant 20 KV-tile iterations. 8 waves x 32 q-rows (2 subtiles of 16).
// K/V staged once per tile, shared by 8 waves; KV re-read factor 4->2.
// LDS 64KB: Ks 16 + Vs 16 + Ps 32.
__global__ __launch_bounds__(512) void attn_fwd(
    const bf16_t* __restrict__ Q, const bf16_t* __restrict__ K,
    const bf16_t* __restrict__ Vt, bf16_t* __restrict__ Out) {
  __shared__ alignas(16) bf16_t Ks[2][64][64];
  __shared__ alignas(16) bf16_t Vs[2][64][64];   // [d][kv]
  __shared__ alignas(16) bf16_t Ps[8][32][64];   // per-wave P[q][kv], swizzled
  const int tid = threadIdx.x, wave = tid >> 6, lane = tid & 63;
  const int lr = lane & 15, lg = lane >> 4;
  const int bx = blockIdx.x;  // 0..1 -> q-super-tiles {bx, 3-bx}
  const int bh = blockIdx.y;
  const int b = bh >> 4, h = bh & 15;
  const bf16_t* Qb = Q + (size_t)bh * 65536;
  const bf16_t* Kb = K + (size_t)bh * 65536;
  const bf16_t* Vb = Vt + (size_t)bh * 65536;

  const int srow = tid >> 3;                    // 0..63
  const int schunk = (tid & 7) ^ (srow & 7);

  auto stage = [&](int bufn, int t) {
    // 512 threads: each issues 1 K-load + 1 V-load (8KB per tile each)
    const bf16_t* gk = Kb + (size_t)(t * 64 + srow) * 64 + schunk * 8;
    gload_lds16(gk, (char*)Ks[bufn] + wave * 1024);
    const bf16_t* gv = Vb + (size_t)srow * 1024 + t * 64 + schunk * 8;
    gload_lds16(gv, (char*)Vs[bufn] + wave * 1024);
  };
  auto ldtile = [&](const bf16_t (*tile)[64], int r, int kk) -> bf16x8 {
    return *(const bf16x8*)((const char*)tile + r * 128 +
                            ((((kk << 2) + lg) ^ (r & 7)) << 4));
  };
  char* psb = (char*)Ps + wave * 4096;

  const int itA = 4 * bx + 4;  // iterations in phase A
  int qt = bx;
  int qr = qt * 256 + wave * 32;
  bf16x8 qf[2][2];
#pragma unroll
  for (int qs = 0; qs < 2; qs++)
#pragma unroll
    for (int kk = 0; kk < 2; kk++)
      qf[qs][kk] = *(const bf16x8*)&Qb[(size_t)(qr + qs * 16 + lr) * 64 + kk * 32 + lg * 8];

  f32x4 acc[2][4];
#pragma unroll
  for (int qs = 0; qs < 2; qs++)
#pragma unroll
    for (int n = 0; n < 4; n++) acc[qs][n] = (f32x4){0.f, 0.f, 0.f, 0.f};
  float m_s[2] = {-1e30f, -1e30f}, l_s[2] = {0.f, 0.f};

  stage(0, 0);
  int buf = 0;
  for (int it = 0; it < 20; ++it) {
    const int t = (it < itA) ? it : it - itA;
    const bool lastOfPhase = (it == itA - 1) || (it == 19);
    const bool diag = (it >= 4 * bx && it < itA) || (it >= 16);
    __syncthreads();
    if (it < 19) {
      const int tn = (it + 1 < itA) ? it + 1 : it + 1 - itA;
      stage(buf ^ 1, tn);
    }

    // S = K @ Q^T (log2 units): s[qs][n][i] = S[kv=16n+4lg+i][q = qs*16+lr]
    f32x4 s[2][4];
#pragma unroll
    for (int qs = 0; qs < 2; qs++)
#pragma unroll
      for (int n = 0; n < 4; n++) s[qs][n] = (f32x4){0.f, 0.f, 0.f, 0.f};
    __builtin_amdgcn_s_setprio(1);
#pragma unroll
    for (int kk = 0; kk < 2; kk++)
#pragma unroll
      for (int n = 0; n < 4; n++) {
        bf16x8 kf = ldtile(Ks[buf], n * 16 + lr, kk);  // shared across qs
        s[0][n] = __builtin_amdgcn_mfma_f32_16x16x32_bf16(kf, qf[0][kk], s[0][n], 0, 0, 0);
        s[1][n] = __builtin_amdgcn_mfma_f32_16x16x32_bf16(kf, qf[1][kk], s[1][n], 0, 0, 0);
      }
    __builtin_amdgcn_s_setprio(0);

    if (diag) {
#pragma unroll
      for (int qs = 0; qs < 2; qs++) {
        const int qa = qr + qs * 16 + lr;
#pragma unroll
        for (int n = 0; n < 4; n++)
#pragma unroll
          for (int i = 0; i < 4; i++) {
            const int kv = t * 64 + n * 16 + 4 * lg + i;
            if (kv > qa) s[qs][n][i] = -1e30f;
          }
      }
    }

#pragma unroll
    for (int qs = 0; qs < 2; qs++) {
      float mx = s[qs][0][0];
#pragma unroll
      for (int n = 0; n < 4; n++)
#pragma unroll
        for (int i = 0; i < 4; i++) mx = fmaxf(mx, s[qs][n][i]);
      mx = fmaxf(mx, __shfl_xor(mx, 16, 64));
      mx = fmaxf(mx, __shfl_xor(mx, 32, 64));
      if (!__all(mx <= m_s[qs] + 8.f)) {  // defer-max: P bounded by 2^8
        const float mnew = fmaxf(m_s[qs], mx);
        const float alpha = exp2f(m_s[qs] - mnew);
        m_s[qs] = mnew;
        l_s[qs] *= alpha;
#pragma unroll
        for (int i = 0; i < 4; i++) {
          const float ai = __shfl(alpha, 4 * lg + i, 64);
#pragma unroll
          for (int n = 0; n < 4; n++) acc[qs][n][i] *= ai;
        }
      }
      float rs = 0.f;
#pragma unroll
      for (int n = 0; n < 4; n++) {
        bf16x4 pw;
#pragma unroll
        for (int i = 0; i < 4; i++) {
          const float pv = exp2f(s[qs][n][i] - m_s[qs]);
          pw[i] = (bf16_t)pv;
          rs += pv;
        }
        *(bf16x4*)(psb + (qs * 16 + lr) * 128 +
                   ((((n << 1) + (lg >> 1)) ^ (lr & 7)) << 4) + ((lg & 1) << 3)) = pw;
      }
      rs += __shfl_xor(rs, 16, 64);
      rs += __shfl_xor(rs, 32, 64);
      l_s[qs] += rs;
    }

    __builtin_amdgcn_s_setprio(1);
#pragma unroll
    for (int kk = 0; kk < 2; kk++) {
      bf16x8 pa0 = *(const bf16x8*)(psb + lr * 128 +
                                    ((((kk << 2) + lg) ^ (lr & 7)) << 4));
      bf16x8 pa1 = *(const bf16x8*)(psb + (16 + lr) * 128 +
                                    ((((kk << 2) + lg) ^ (lr & 7)) << 4));
#pragma unroll
      for (int n = 0; n < 4; n++) {
        bf16x8 vb = ldtile(Vs[buf], n * 16 + lr, kk);  // shared across qs
        acc[0][n] = __builtin_amdgcn_mfma_f32_16x16x32_bf16(pa0, vb, acc[0][n], 0, 0, 0);
        acc[1][n] = __builtin_amdgcn_mfma_f32_16x16x32_bf16(pa1, vb, acc[1][n], 0, 0, 0);
      }
    }
    __builtin_amdgcn_s_setprio(0);

    if (lastOfPhase) {
#pragma unroll
      for (int qs = 0; qs < 2; qs++) {
        const float invl = 1.f / l_s[qs];
#pragma unroll
        for (int i = 0; i < 4; i++) {
          const float inv_i = __shfl(invl, 4 * lg + i, 64);
          const int qa = qr + qs * 16 + 4 * lg + i;
#pragma unroll
          for (int n = 0; n < 4; n++)
            Out[((size_t)b * 1024 + qa) * 1024 + h * 64 + n * 16 + lr] =
                (bf16_t)(acc[qs][n][i] * inv_i);
        }
      }
      if (it == itA - 1) {  // switch to phase B (q-super-tile 3-bx)
        qt = 3 - bx;
        qr = qt * 256 + wave * 32;
#pragma unroll
        for (int qs = 0; qs < 2; qs++)
#pragma unroll
          for (int kk = 0; kk < 2; kk++)
            qf[qs][kk] =
                *(const bf16x8*)&Qb[(size_t)(qr + qs * 16 + lr) * 64 + kk * 32 + lg * 8];
#pragma unroll
        for (int qs = 0; qs < 2; qs++) {
#pragma unroll
          for (int n = 0; n < 4; n++) acc[qs][n] = (f32x4){0.f, 0.f, 0.f, 0.f};
          m_s[qs] = -1e30f;
          l_s[qs] = 0.f;
        }
      }
    }
    buf ^= 1;
  }
}

// ---------------- launch ----------------
extern "C" void kernel_launch(void* const* d_in, const int* in_sizes, int n_in,
                              void* d_out, int out_size, void* d_ws, size_t ws_size,
                              hipStream_t stream) {
  const float* x = (const float*)d_in[0];
  const float* w_in = (const float*)d_in[1];
  const float* b_in = (const float*)d_in[2];
  const float* w_out = (const float*)d_in[3];
  const float* b_out = (const float*)d_in[4];
  const float* w_c = (const float*)d_in[5];
  const float* b_c = (const float*)d_in[6];
  float* out = (float*)d_out;

  const int M = 8192, E = 1024, N3 = 3072;
  char* ws = (char*)d_ws;
  size_t off = 0;
  auto alloc = [&](size_t bytes) {
    char* p = ws + off;
    off += (bytes + 255) & ~(size_t)255;
    return p;
  };
  bf16_t* xb = (bf16_t*)alloc((size_t)M * E * 2);
  bf16_t* wqb = (bf16_t*)alloc((size_t)N3 * E * 2);
  bf16_t* wcb = (bf16_t*)alloc((size_t)E * E * 2);
  bf16_t* wotb = (bf16_t*)alloc((size_t)E * E * 2);    // w_out TRANSPOSED bf16
  bf16_t* wcombb = (bf16_t*)alloc((size_t)E * E * 2);  // Wc @ Wo, bf16
  float* b2 = (float*)alloc((size_t)E * 4);            // bo @ Wc^T + bc
  bf16_t* Qs = (bf16_t*)alloc((size_t)M * E * 2);
  bf16_t* Kc = (bf16_t*)alloc((size_t)M * E * 2);
  bf16_t* Vt = (bf16_t*)alloc((size_t)M * E * 2);
  bf16_t* AO = (bf16_t*)alloc((size_t)M * E * 2);

  const int na4 = M * E / 4, nb4 = N3 * E / 4, nc4 = E * E / 4;
  const int ncvt = (na4 + nb4 + nc4) / 256;  // 12288, exact
  prep<<<ncvt + 1024 + 256, 256, 0, stream>>>(
      x, xb, na4, w_in, wqb, nb4, w_c, wcb, nc4, w_out, wotb, b_out, b_c, b2);

  // Wcomb = Wc @ Wo  (A = Wc row-major, B = Wo^T so A@B^T = Wc@Wo)
  gemm_db<<<dim3(E / 128, E / 128), 256, 0, stream>>>(
      wcb, wotb, wcombb, E, E, E);

  gemm_qkv<<<768, 512, 0, stream>>>(xb, wqb, b_in, Qs, Kc, Vt);
  attn_fwd<<<dim3(2, 128), 512, 0, stream>>>(Qs, Kc, Vt, AO);
  // final = AO @ Wcomb^T + b2  (replaces out_proj AND c_proj)
  gemm_fin<<<256, 512, 0, stream>>>(AO, wcombb, b2, out);
}

// Round 18
// 159.970 us; speedup vs baseline: 1.0376x; 1.0376x over previous
//
#include <hip/hip_runtime.h>
#include <hip/hip_bf16.h>
#include <stdint.h>

typedef __bf16 bf16_t;
typedef __bf16 bf16x8 __attribute__((ext_vector_type(8)));
typedef __bf16 bf16x4 __attribute__((ext_vector_type(4)));
typedef float f32x4 __attribute__((ext_vector_type(4)));

#define DEVI static __device__ __forceinline__
#define SCHED0 __builtin_amdgcn_sched_barrier(0)
#define VMCNT0 asm volatile("s_waitcnt vmcnt(0)" ::: "memory")

// async global->LDS, 16B per lane. LDS dest = wave-uniform base + lane*16 (HW).
DEVI void gload_lds16(const void* g, void* lds) {
  __builtin_amdgcn_global_load_lds(
      (const __attribute__((address_space(1))) unsigned int*)g,
      (__attribute__((address_space(3))) unsigned int*)lds, 16, 0, 0);
}

// ---------------- merged prep: cvt x/w_in/w_c + transposed cvt of w_out +
// fused bias b2 = bc + bo @ Wc^T, one launch, block-range partitioned -------
__global__ void prep(const float* __restrict__ x, bf16_t* __restrict__ xb, int na4,
                     const float* __restrict__ w_in, bf16_t* __restrict__ wqb, int nb4,
                     const float* __restrict__ w_c, bf16_t* __restrict__ wcb, int nc4,
                     const float* __restrict__ w_out, bf16_t* __restrict__ wotb,
                     const float* __restrict__ bo, const float* __restrict__ bc,
                     float* __restrict__ b2) {
  __shared__ float ls[32][36];
  const int bid = blockIdx.x, tid = threadIdx.x;
  const int ncvt = (na4 + nb4 + nc4) >> 8;  // exact multiple of 256
  if (bid < ncvt) {
    int j = bid * 256 + tid;
    const float* src;
    bf16_t* dst;
    if (j < na4) {
      src = x; dst = xb;
    } else {
      j -= na4;
      if (j < nb4) {
        src = w_in; dst = wqb;
      } else {
        j -= nb4;
        src = w_c; dst = wcb;
      }
    }
    float4 v = ((const float4*)src)[j];
    bf16x4 o;
    o[0] = (bf16_t)v.x; o[1] = (bf16_t)v.y; o[2] = (bf16_t)v.z; o[3] = (bf16_t)v.w;
    ((bf16x4*)dst)[j] = o;
  } else if (bid < ncvt + 1024) {
    // 32x32 transpose-cvt tile of w_out (1024x1024)
    const int idx = bid - ncvt;
    const int C0 = (idx & 31) * 32, R0 = (idx >> 5) * 32;
    {
      const int r = tid >> 3, c4 = (tid & 7) * 4;
      float4 v = *(const float4*)&w_out[(size_t)(R0 + r) * 1024 + C0 + c4];
      ls[r][c4 + 0] = v.x; ls[r][c4 + 1] = v.y; ls[r][c4 + 2] = v.z; ls[r][c4 + 3] = v.w;
    }
    __syncthreads();
    {
      const int c = tid >> 3, r4 = (tid & 7) * 4;
      bf16x4 o;
#pragma unroll
      for (int j = 0; j < 4; j++) o[j] = (bf16_t)ls[r4 + j][c];
      *(bf16x4*)&wotb[(size_t)(C0 + c) * 1024 + R0 + r4] = o;
    }
  } else {
    // bias2k: 256 blocks x 4 waves -> 1024 outputs
    const int wid = ((bid - ncvt - 1024) << 2) + (tid >> 6);
    const int ln = tid & 63;
    float s = 0.f;
    for (int k = ln; k < 1024; k += 64) s += bo[k] * w_c[(size_t)wid * 1024 + k];
#pragma unroll
    for (int o = 32; o; o >>= 1) s += __shfl_xor(s, o, 64);
    if (ln == 0) b2[wid] = s + bc[wid];
  }
}

// ============ 128x256 QKV GEMM, 2-phase, 8 waves (proven form) =============
// C[8192,3072] = A @ B^T + bias -> scattered Q/K/V^T. Wave tile 64x64.
// LDS 96KB, 1 block/CU, single barrier per K-step.
__global__ __launch_bounds__(512, 2) void gemm_qkv(
    const bf16_t* __restrict__ A, const bf16_t* __restrict__ B,
    const float* __restrict__ bias,
    bf16_t* __restrict__ qo, bf16_t* __restrict__ ko, bf16_t* __restrict__ vo) {
  __shared__ alignas(16) char lds[98304];  // A: [0,32K) dbuf, B: [32K,96K) dbuf
  const int K = 1024;
  const int tid = threadIdx.x;
  const int wave = tid >> 6, lane = tid & 63;
  const int lr = lane & 15, lg = (lane >> 4) & 3;
  const int wm = wave >> 2, wn = wave & 3;

  // L2-chunked XCD mapping: xcd owns 8 bm-tiles (A-chunk 2MB, L2-fits);
  // consecutive idx walks bm within chunk (B-panel 512KB shared).
  const int lin = blockIdx.x;
  const int xcd = lin & 7, idx = lin >> 3;        // idx 0..95
  const int bm = (xcd * 8 + (idx & 7)) * 128;
  const int bn = (idx >> 3) * 256;

  const int srow = tid >> 3;                      // 0..63
  const int schunk = (tid & 7) ^ (srow & 7);      // pre-swizzled global chunk

  auto stage = [&](int buf, int t) {
#pragma unroll
    for (int u = 0; u < 2; u++) {
      const bf16_t* ga = A + (size_t)(bm + u * 64 + srow) * K + t * 64 + schunk * 8;
      gload_lds16(ga, lds + buf * 16384 + u * 8192 + wave * 1024);
    }
#pragma unroll
    for (int u = 0; u < 4; u++) {
      const bf16_t* gb = B + (size_t)(bn + u * 64 + srow) * K + t * 64 + schunk * 8;
      gload_lds16(gb, lds + 32768 + buf * 32768 + u * 8192 + wave * 1024);
    }
  };
  auto ldA = [&](int buf, int mf, int kk) -> bf16x8 {
    const int row = wm * 64 + mf * 16 + lr;
    return *(const bf16x8*)(lds + buf * 16384 + row * 128 +
                            ((((kk << 2) + lg) ^ (row & 7)) << 4));
  };
  auto ldB = [&](int buf, int nf, int kk) -> bf16x8 {
    const int row = wn * 64 + nf * 16 + lr;
    return *(const bf16x8*)(lds + 32768 + buf * 32768 + row * 128 +
                            ((((kk << 2) + lg) ^ (row & 7)) << 4));
  };

  f32x4 acc[4][4];
#pragma unroll
  for (int m = 0; m < 4; m++)
#pragma unroll
    for (int n = 0; n < 4; n++) acc[m][n] = (f32x4){0.f, 0.f, 0.f, 0.f};

  stage(0, 0);
  VMCNT0;
  __builtin_amdgcn_s_barrier();
  SCHED0;

  auto kstep = [&](int buf, int t, bool pre) {
    if (pre) stage(buf ^ 1, t + 1);  // prefetch: whole compute phase to land
    SCHED0;
#pragma unroll
    for (int kk = 0; kk < 2; kk++) {
      bf16x8 af[4], bfr[4];
#pragma unroll
      for (int m = 0; m < 4; m++) af[m] = ldA(buf, m, kk);
#pragma unroll
      for (int n = 0; n < 4; n++) bfr[n] = ldB(buf, n, kk);
#pragma unroll
      for (int m = 0; m < 4; m++)
#pragma unroll
        for (int n = 0; n < 4; n++)
          acc[m][n] = __builtin_amdgcn_mfma_f32_16x16x32_bf16(af[m], bfr[n], acc[m][n], 0, 0, 0);
    }
    SCHED0;
    VMCNT0;
    __builtin_amdgcn_s_barrier();
    SCHED0;
  };
  for (int t = 0; t < 16; t += 2) {
    kstep(0, t, true);
    kstep(1, t + 1, t + 2 < 16);
  }

  // ---- epilogue: LDS roundtrip, coalesced scatter to Q/K/V^T -------------
  const int which = bn >> 10;  // 0=Q 1=K 2=V (256-tile wholly in one section)
  if (which != 2) {
    bf16_t(*ep)[264] = (bf16_t(*)[264])lds;  // [128][264] = 67.6 KB
#pragma unroll
    for (int nf = 0; nf < 4; nf++) {
      const int col = wn * 64 + nf * 16 + lr;
      const float bv = bias[bn + col];
#pragma unroll
      for (int mf = 0; mf < 4; mf++)
#pragma unroll
        for (int i = 0; i < 4; i++) {
          const int row = wm * 64 + mf * 16 + lg * 4 + i;
          float v = acc[mf][nf][i] + bv;
          if (which == 0) v *= 0.18033688f;  // fold (1/sqrt(64))*log2(e)
          ep[row][col] = (bf16_t)v;
        }
    }
    __syncthreads();
#pragma unroll
    for (int itr = 0; itr < 8; itr++) {
      const int unit = itr * 512 + tid;  // 128 rows x 32 chunks
      const int row = unit >> 5, c0 = (unit & 31) * 8;
      bf16x8 val = *(const bf16x8*)&ep[row][c0];
      const int gr = bm + row, b = gr >> 10, t = gr & 1023;
      const int e = bn + c0, h = (e & 1023) >> 6, d = e & 63;
      bf16_t* dst = (which == 0 ? qo : ko) + ((size_t)(b * 16 + h) * 1024 + t) * 64 + d;
      *(bf16x8*)dst = val;
    }
  } else {
    bf16_t(*ep)[136] = (bf16_t(*)[136])lds;  // transposed [256][136] = 69.6 KB
#pragma unroll
    for (int nf = 0; nf < 4; nf++) {
      const int col = wn * 64 + nf * 16 + lr;
      const float bv = bias[bn + col];
#pragma unroll
      for (int mf = 0; mf < 4; mf++)
#pragma unroll
        for (int i = 0; i < 4; i++) {
          const int row = wm * 64 + mf * 16 + lg * 4 + i;
          ep[col][row] = (bf16_t)(acc[mf][nf][i] + bv);
        }
    }
    __syncthreads();
#pragma unroll
    for (int itr = 0; itr < 8; itr++) {
      const int unit = itr * 512 + tid;  // 256 d-rows x 16 chunks of t
      const int r = unit >> 4, c0 = (unit & 15) * 8;
      bf16x8 val = *(const bf16x8*)&ep[r][c0];
      const int e = (bn - 2048) + r, h = e >> 6, d = e & 63;
      const int gt = bm + c0, b = gt >> 10, t = gt & 1023;
      bf16_t* dst = vo + ((size_t)(b * 16 + h) * 64 + d) * 1024 + t;
      *(bf16x8*)dst = val;
    }
  }
}

// ============ 128x256 FINAL GEMM, f32 out (proven form) ====================
__global__ __launch_bounds__(512, 2) void gemm_fin(
    const bf16_t* __restrict__ A, const bf16_t* __restrict__ B,
    const float* __restrict__ bias, float* __restrict__ Cout) {
  __shared__ alignas(16) char lds[98304];
  const int K = 1024, N = 1024;
  const int tid = threadIdx.x;
  const int wave = tid >> 6, lane = tid & 63;
  const int lr = lane & 15, lg = (lane >> 4) & 3;
  const int wm = wave >> 2, wn = wave & 3;

  const int lin = blockIdx.x;                 // 0..255
  const int xcd = lin & 7, idx = lin >> 3;    // idx 0..31
  const int bm = (xcd * 8 + (idx & 7)) * 128;
  const int bn = (idx >> 3) * 256;

  const int srow = tid >> 3;
  const int schunk = (tid & 7) ^ (srow & 7);

  auto stage = [&](int buf, int t) {
#pragma unroll
    for (int u = 0; u < 2; u++) {
      const bf16_t* ga = A + (size_t)(bm + u * 64 + srow) * K + t * 64 + schunk * 8;
      gload_lds16(ga, lds + buf * 16384 + u * 8192 + wave * 1024);
    }
#pragma unroll
    for (int u = 0; u < 4; u++) {
      const bf16_t* gb = B + (size_t)(bn + u * 64 + srow) * K + t * 64 + schunk * 8;
      gload_lds16(gb, lds + 32768 + buf * 32768 + u * 8192 + wave * 1024);
    }
  };
  auto ldA = [&](int buf, int mf, int kk) -> bf16x8 {
    const int row = wm * 64 + mf * 16 + lr;
    return *(const bf16x8*)(lds + buf * 16384 + row * 128 +
                            ((((kk << 2) + lg) ^ (row & 7)) << 4));
  };
  auto ldB = [&](int buf, int nf, int kk) -> bf16x8 {
    const int row = wn * 64 + nf * 16 + lr;
    return *(const bf16x8*)(lds + 32768 + buf * 32768 + row * 128 +
                            ((((kk << 2) + lg) ^ (row & 7)) << 4));
  };

  f32x4 acc[4][4];
#pragma unroll
  for (int m = 0; m < 4; m++)
#pragma unroll
    for (int n = 0; n < 4; n++) acc[m][n] = (f32x4){0.f, 0.f, 0.f, 0.f};

  stage(0, 0);
  VMCNT0;
  __builtin_amdgcn_s_barrier();
  SCHED0;

  auto kstep = [&](int buf, int t, bool pre) {
    if (pre) stage(buf ^ 1, t + 1);
    SCHED0;
#pragma unroll
    for (int kk = 0; kk < 2; kk++) {
      bf16x8 af[4], bfr[4];
#pragma unroll
      for (int m = 0; m < 4; m++) af[m] = ldA(buf, m, kk);
#pragma unroll
      for (int n = 0; n < 4; n++) bfr[n] = ldB(buf, n, kk);
#pragma unroll
      for (int m = 0; m < 4; m++)
#pragma unroll
        for (int n = 0; n < 4; n++)
          acc[m][n] = __builtin_amdgcn_mfma_f32_16x16x32_bf16(af[m], bfr[n], acc[m][n], 0, 0, 0);
    }
    SCHED0;
    VMCNT0;
    __builtin_amdgcn_s_barrier();
    SCHED0;
  };
  for (int t = 0; t < 16; t += 2) {
    kstep(0, t, true);
    kstep(1, t + 1, t + 2 < 16);
  }

  // 2-pass coalesced f32 epilogue: [64][264] f32 = 67.6 KB
  float(*epf)[264] = (float(*)[264])lds;
#pragma unroll
  for (int p = 0; p < 2; ++p) {
    if (wm == p) {
#pragma unroll
      for (int nf = 0; nf < 4; nf++) {
        const int col = wn * 64 + nf * 16 + lr;
        const float bv = bias[bn + col];
#pragma unroll
        for (int mf = 0; mf < 4; mf++)
#pragma unroll
          for (int i = 0; i < 4; i++)
            epf[mf * 16 + lg * 4 + i][col] = acc[mf][nf][i] + bv;
      }
    }
    __syncthreads();
#pragma unroll
    for (int itr = 0; itr < 8; ++itr) {
      const int unit = itr * 512 + tid;  // 64 rows x 64 float4
      const int row = unit >> 6, c4 = (unit & 63) * 4;
      float4 v = *(const float4*)&epf[row][c4];
      *(float4*)&Cout[(size_t)(bm + p * 64 + row) * N + bn + c4] = v;
    }
    __syncthreads();
  }
}

// ---------------- 128x128 double-buffered GEMM (wcomb only) ----------------
__global__ __launch_bounds__(256, 2) void gemm_db(
    const bf16_t* __restrict__ A, const bf16_t* __restrict__ B,
    bf16_t* __restrict__ Cout, int M, int N, int K) {
  __shared__ alignas(16) char lds[65536];
  const int tid = threadIdx.x;
  const int wave = tid >> 6, lane = tid & 63;
  const int lr = lane & 15, lg = lane >> 4;
  const int wr = wave >> 1, wc = wave & 1;

  const int gx = gridDim.x;
  const int lin = blockIdx.y * gx + blockIdx.x;
  const int xcd = lin & 7, idx = lin >> 3;
  const int bmx = gx >> 3;
  const int bm = (xcd * bmx + (bmx > 1 ? idx % bmx : 0)) * 128;
  const int bn = (bmx > 1 ? idx / bmx : idx) * 128;

  const int srow = tid >> 3;
  const int schunk = (tid & 7) ^ (srow & 7);

  auto stage = [&](int buf, int t) {
#pragma unroll
    for (int i = 0; i < 4; i++) {
      const bf16_t* ga = A + (size_t)(bm + srow + i * 32) * K + t * 64 + schunk * 8;
      gload_lds16(ga, lds + buf * 16384 + i * 4096 + wave * 1024);
      const bf16_t* gb = B + (size_t)(bn + srow + i * 32) * K + t * 64 + schunk * 8;
      gload_lds16(gb, lds + 32768 + buf * 16384 + i * 4096 + wave * 1024);
    }
  };
  auto ldA = [&](int buf, int mf, int kk) -> bf16x8 {
    const int row = wr * 64 + mf * 16 + lr;
    return *(const bf16x8*)(lds + buf * 16384 + row * 128 +
                            ((((kk << 2) + lg) ^ (row & 7)) << 4));
  };
  auto ldB = [&](int buf, int nf, int kk) -> bf16x8 {
    const int row = wc * 64 + nf * 16 + lr;
    return *(const bf16x8*)(lds + 32768 + buf * 16384 + row * 128 +
                            ((((kk << 2) + lg) ^ (row & 7)) << 4));
  };

  f32x4 acc[4][4];
#pragma unroll
  for (int m = 0; m < 4; m++)
#pragma unroll
    for (int n = 0; n < 4; n++) acc[m][n] = (f32x4){0.f, 0.f, 0.f, 0.f};

  const int nK = K >> 6;

  stage(0, 0);
  VMCNT0;
  __builtin_amdgcn_s_barrier();
  SCHED0;

  auto kstep = [&](int buf, int t, bool pre) {
    if (pre) stage(buf ^ 1, t + 1);
    SCHED0;
#pragma unroll
    for (int kk = 0; kk < 2; kk++) {
      bf16x8 af[4], bfr[4];
#pragma unroll
      for (int m = 0; m < 4; m++) af[m] = ldA(buf, m, kk);
#pragma unroll
      for (int n = 0; n < 4; n++) bfr[n] = ldB(buf, n, kk);
#pragma unroll
      for (int m = 0; m < 4; m++)
#pragma unroll
        for (int n = 0; n < 4; n++)
          acc[m][n] = __builtin_amdgcn_mfma_f32_16x16x32_bf16(af[m], bfr[n], acc[m][n], 0, 0, 0);
    }
    SCHED0;
    VMCNT0;
    __builtin_amdgcn_s_barrier();
    SCHED0;
  };
  for (int t = 0; t < nK; t += 2) {
    kstep(0, t, true);
    kstep(1, t + 1, t + 2 < nK);
  }

  bf16_t(*ep)[132] = (bf16_t(*)[132])lds;
#pragma unroll
  for (int nf = 0; nf < 4; nf++) {
    const int col = wc * 64 + nf * 16 + lr;
#pragma unroll
    for (int mf = 0; mf < 4; mf++)
#pragma unroll
      for (int i = 0; i < 4; i++)
        ep[wr * 64 + mf * 16 + lg * 4 + i][col] = (bf16_t)acc[mf][nf][i];
  }
  __syncthreads();
#pragma unroll
  for (int rr = 0; rr < 8; rr++) {
    const int row = rr * 16 + (tid >> 4);
    const int c0 = (tid & 15) * 8;
    bf16x8 val = *(const bf16x8*)&ep[row][c0];
    *(bf16x8*)&((bf16_t*)Cout)[(size_t)(bm + row) * N + bn + c0] = val;
  }
}

// ---------------- causal flash attention v3: QBLK=128, K+V staged ----------
// 4 waves x 32 q-rows, 2 blocks/CU, grid (4,128), constant 18 iterations.
__global__ __launch_bounds__(256) void attn_fwd(
    const bf16_t* __restrict__ Q, const bf16_t* __restrict__ K,
    const bf16_t* __restrict__ Vt, bf16_t* __restrict__ Out) {
  __shared__ alignas(16) bf16_t Ks[2][64][64];
  __shared__ alignas(16) bf16_t Vs[2][64][64];   // [d][kv]
  __shared__ alignas(16) bf16_t Ps[4][32][64];   // per-wave P[q][kv], swizzled
  const int tid = threadIdx.x, wave = tid >> 6, lane = tid & 63;
  const int lr = lane & 15, lg = lane >> 4;
  const int bx = blockIdx.x;  // 0..3 -> q-super-tiles {bx, 7-bx}
  const int bh = blockIdx.y;
  const int b = bh >> 4, h = bh & 15;
  const bf16_t* Qb = Q + (size_t)bh * 65536;
  const bf16_t* Kb = K + (size_t)bh * 65536;
  const bf16_t* Vb = Vt + (size_t)bh * 65536;

  const int srow = tid >> 3;
  const int schunk = (tid & 7) ^ (srow & 7);

  auto stage = [&](int bufn, int t) {
#pragma unroll
    for (int i = 0; i < 2; i++) {
      const bf16_t* g = Kb + (size_t)(t * 64 + srow + i * 32) * 64 + schunk * 8;
      gload_lds16(g, (char*)Ks[bufn] + i * 4096 + wave * 1024);
    }
#pragma unroll
    for (int i = 0; i < 2; i++) {
      const bf16_t* g = Vb + (size_t)(srow + i * 32) * 1024 + t * 64 + schunk * 8;
      gload_lds16(g, (char*)Vs[bufn] + i * 4096 + wave * 1024);
    }
  };
  auto ldtile = [&](const bf16_t (*tile)[64], int r, int kk) -> bf16x8 {
    return *(const bf16x8*)((const char*)tile + r * 128 +
                            ((((kk << 2) + lg) ^ (r & 7)) << 4));
  };
  char* psb = (char*)Ps + wave * 4096;

  const int itA = 2 * bx + 2;  // iterations in phase A
  int qt = bx;
  int qr = qt * 128 + wave * 32;
  bf16x8 qf[2][2];
#pragma unroll
  for (int qs = 0; qs < 2; qs++)
#pragma unroll
    for (int kk = 0; kk < 2; kk++)
      qf[qs][kk] = *(const bf16x8*)&Qb[(size_t)(qr + qs * 16 + lr) * 64 + kk * 32 + lg * 8];

  f32x4 acc[2][4];
#pragma unroll
  for (int qs = 0; qs < 2; qs++)
#pragma unroll
    for (int n = 0; n < 4; n++) acc[qs][n] = (f32x4){0.f, 0.f, 0.f, 0.f};
  float m_s[2] = {-1e30f, -1e30f}, l_s[2] = {0.f, 0.f};

  stage(0, 0);
  int buf = 0;
  for (int it = 0; it < 18; ++it) {
    const int t = (it < itA) ? it : it - itA;
    const bool lastOfPhase = (it == itA - 1) || (it == 17);
    const bool diag = (it >= 2 * bx && it < itA) || (it >= 16);
    __syncthreads();
    if (it < 17) {
      const int tn = (it + 1 < itA) ? it + 1 : it + 1 - itA;
      stage(buf ^ 1, tn);
    }

    f32x4 s[2][4];
#pragma unroll
    for (int qs = 0; qs < 2; qs++)
#pragma unroll
      for (int n = 0; n < 4; n++) s[qs][n] = (f32x4){0.f, 0.f, 0.f, 0.f};
    __builtin_amdgcn_s_setprio(1);
#pragma unroll
    for (int kk = 0; kk < 2; kk++)
#pragma unroll
      for (int n = 0; n < 4; n++) {
        bf16x8 kf = ldtile(Ks[buf], n * 16 + lr, kk);  // shared across qs
        s[0][n] = __builtin_amdgcn_mfma_f32_16x16x32_bf16(kf, qf[0][kk], s[0][n], 0, 0, 0);
        s[1][n] = __builtin_amdgcn_mfma_f32_16x16x32_bf16(kf, qf[1][kk], s[1][n], 0, 0, 0);
      }
    __builtin_amdgcn_s_setprio(0);

    if (diag) {
#pragma unroll
      for (int qs = 0; qs < 2; qs++) {
        const int qa = qr + qs * 16 + lr;
#pragma unroll
        for (int n = 0; n < 4; n++)
#pragma unroll
          for (int i = 0; i < 4; i++) {
            const int kv = t * 64 + n * 16 + 4 * lg + i;
            if (kv > qa) s[qs][n][i] = -1e30f;
          }
      }
    }

#pragma unroll
    for (int qs = 0; qs < 2; qs++) {
      float mx = s[qs][0][0];
#pragma unroll
      for (int n = 0; n < 4; n++)
#pragma unroll
        for (int i = 0; i < 4; i++) mx = fmaxf(mx, s[qs][n][i]);
      mx = fmaxf(mx, __shfl_xor(mx, 16, 64));
      mx = fmaxf(mx, __shfl_xor(mx, 32, 64));
      if (!__all(mx <= m_s[qs] + 8.f)) {  // defer-max: P bounded by 2^8
        const float mnew = fmaxf(m_s[qs], mx);
        const float alpha = exp2f(m_s[qs] - mnew);
        m_s[qs] = mnew;
        l_s[qs] *= alpha;
#pragma unroll
        for (int i = 0; i < 4; i++) {
          const float ai = __shfl(alpha, 4 * lg + i, 64);
#pragma unroll
          for (int n = 0; n < 4; n++) acc[qs][n][i] *= ai;
        }
      }
      float rs = 0.f;
#pragma unroll
      for (int n = 0; n < 4; n++) {
        bf16x4 pw;
#pragma unroll
        for (int i = 0; i < 4; i++) {
          const float pv = exp2f(s[qs][n][i] - m_s[qs]);
          pw[i] = (bf16_t)pv;
          rs += pv;
        }
        *(bf16x4*)(psb + (qs * 16 + lr) * 128 +
                   ((((n << 1) + (lg >> 1)) ^ (lr & 7)) << 4) + ((lg & 1) << 3)) = pw;
      }
      rs += __shfl_xor(rs, 16, 64);
      rs += __shfl_xor(rs, 32, 64);
      l_s[qs] += rs;
    }

    __builtin_amdgcn_s_setprio(1);
#pragma unroll
    for (int kk = 0; kk < 2; kk++) {
      bf16x8 pa0 = *(const bf16x8*)(psb + lr * 128 +
                                    ((((kk << 2) + lg) ^ (lr & 7)) << 4));
      bf16x8 pa1 = *(const bf16x8*)(psb + (16 + lr) * 128 +
                                    ((((kk << 2) + lg) ^ (lr & 7)) << 4));
#pragma unroll
      for (int n = 0; n < 4; n++) {
        bf16x8 vb = ldtile(Vs[buf], n * 16 + lr, kk);  // shared across qs
        acc[0][n] = __builtin_amdgcn_mfma_f32_16x16x32_bf16(pa0, vb, acc[0][n], 0, 0, 0);
        acc[1][n] = __builtin_amdgcn_mfma_f32_16x16x32_bf16(pa1, vb, acc[1][n], 0, 0, 0);
      }
    }
    __builtin_amdgcn_s_setprio(0);

    if (lastOfPhase) {
#pragma unroll
      for (int qs = 0; qs < 2; qs++) {
        const float invl = 1.f / l_s[qs];
#pragma unroll
        for (int i = 0; i < 4; i++) {
          const float inv_i = __shfl(invl, 4 * lg + i, 64);
          const int qa = qr + qs * 16 + 4 * lg + i;
#pragma unroll
          for (int n = 0; n < 4; n++)
            Out[((size_t)b * 1024 + qa) * 1024 + h * 64 + n * 16 + lr] =
                (bf16_t)(acc[qs][n][i] * inv_i);
        }
      }
      if (it == itA - 1) {  // switch to phase B (q-super-tile 7-bx)
        qt = 7 - bx;
        qr = qt * 128 + wave * 32;
#pragma unroll
        for (int qs = 0; qs < 2; qs++)
#pragma unroll
          for (int kk = 0; kk < 2; kk++)
            qf[qs][kk] =
                *(const bf16x8*)&Qb[(size_t)(qr + qs * 16 + lr) * 64 + kk * 32 + lg * 8];
#pragma unroll
        for (int qs = 0; qs < 2; qs++) {
#pragma unroll
          for (int n = 0; n < 4; n++) acc[qs][n] = (f32x4){0.f, 0.f, 0.f, 0.f};
          m_s[qs] = -1e30f;
          l_s[qs] = 0.f;
        }
      }
    }
    buf ^= 1;
  }
}

// ---------------- launch ----------------
extern "C" void kernel_launch(void* const* d_in, const int* in_sizes, int n_in,
                              void* d_out, int out_size, void* d_ws, size_t ws_size,
                              hipStream_t stream) {
  const float* x = (const float*)d_in[0];
  const float* w_in = (const float*)d_in[1];
  const float* b_in = (const float*)d_in[2];
  const float* w_out = (const float*)d_in[3];
  const float* b_out = (const float*)d_in[4];
  const float* w_c = (const float*)d_in[5];
  const float* b_c = (const float*)d_in[6];
  float* out = (float*)d_out;

  const int M = 8192, E = 1024, N3 = 3072;
  char* ws = (char*)d_ws;
  size_t off = 0;
  auto alloc = [&](size_t bytes) {
    char* p = ws + off;
    off += (bytes + 255) & ~(size_t)255;
    return p;
  };
  bf16_t* xb = (bf16_t*)alloc((size_t)M * E * 2);
  bf16_t* wqb = (bf16_t*)alloc((size_t)N3 * E * 2);
  bf16_t* wcb = (bf16_t*)alloc((size_t)E * E * 2);
  bf16_t* wotb = (bf16_t*)alloc((size_t)E * E * 2);    // w_out TRANSPOSED bf16
  bf16_t* wcombb = (bf16_t*)alloc((size_t)E * E * 2);  // Wc @ Wo, bf16
  float* b2 = (float*)alloc((size_t)E * 4);            // bo @ Wc^T + bc
  bf16_t* Qs = (bf16_t*)alloc((size_t)M * E * 2);
  bf16_t* Kc = (bf16_t*)alloc((size_t)M * E * 2);
  bf16_t* Vt = (bf16_t*)alloc((size_t)M * E * 2);
  bf16_t* AO = (bf16_t*)alloc((size_t)M * E * 2);

  const int na4 = M * E / 4, nb4 = N3 * E / 4, nc4 = E * E / 4;
  const int ncvt = (na4 + nb4 + nc4) / 256;  // 12288, exact
  prep<<<ncvt + 1024 + 256, 256, 0, stream>>>(
      x, xb, na4, w_in, wqb, nb4, w_c, wcb, nc4, w_out, wotb, b_out, b_c, b2);

  // Wcomb = Wc @ Wo  (A = Wc row-major, B = Wo^T so A@B^T = Wc@Wo)
  gemm_db<<<dim3(E / 128, E / 128), 256, 0, stream>>>(
      wcb, wotb, wcombb, E, E, E);

  gemm_qkv<<<768, 512, 0, stream>>>(xb, wqb, b_in, Qs, Kc, Vt);
  attn_fwd<<<dim3(4, 128), 256, 0, stream>>>(Qs, Kc, Vt, AO);
  // final = AO @ Wcomb^T + b2  (replaces out_proj AND c_proj)
  gemm_fin<<<256, 512, 0, stream>>>(AO, wcombb, b2, out);
}